// Round 1
// baseline (162.708 us; speedup 1.0000x reference)
//
#include <hip/hip_runtime.h>
#include <hip/hip_bf16.h>
#include <type_traits>

typedef __bf16 bf16_t;
typedef __bf16 bf16x4 __attribute__((ext_vector_type(4)));
typedef __bf16 bf16x8 __attribute__((ext_vector_type(8)));
typedef float  f32x4  __attribute__((ext_vector_type(4)));

__device__ __forceinline__ f32x4 mfma16(bf16x8 a, bf16x8 b, f32x4 c) {
  return __builtin_amdgcn_mfma_f32_16x16x32_bf16(a, b, c, 0, 0, 0);
}

static constexpr int NB = 8;
static constexpr int LQ = 1024;
static constexpr int LKk = 1024;
static constexpr int DMODEL = 512;
static constexpr int NH = 8;
static constexpr int DKH = 64;
static constexpr int MROWS = NB * LQ;   // 8192

// swizzled byte offset for [R][128B] row-major LDS tiles (G4 XOR swizzle)
__device__ __forceinline__ int swz(int row, int byte) {
  return row * 128 + (byte ^ ((row & 7) << 4));
}

// C[M,N] = act(A[M,K] @ W[K,N] + bias)   A: f32 or bf16, W/bias: f32, C: bf16 or f32
template<int K, bool RELU, typename AT, typename OT>
__global__ __launch_bounds__(256)
void gemm_bias_act(const AT* __restrict__ A, const float* __restrict__ W,
                   const float* __restrict__ bias, OT* __restrict__ C, int N)
{
  __shared__ alignas(16) char Alds[64 * 128];
  __shared__ alignas(16) char Wlds[64 * 128];
  const int t = threadIdx.x;
  const int l = t & 63, w = t >> 6;
  const int m0 = blockIdx.y * 64, n0 = blockIdx.x * 64;

  f32x4 acc[4] = {};
  for (int k0 = 0; k0 < K; k0 += 64) {
    __syncthreads();
    // stage A tile [64 rows][64 k] as bf16 (16 elems per thread)
    {
      const int row = t >> 2, c0 = (t & 3) * 16;
      if constexpr (std::is_same<AT, float>::value) {
        const float4* ap = reinterpret_cast<const float4*>(A + (size_t)(m0 + row) * K + k0 + c0);
        #pragma unroll
        for (int j = 0; j < 4; ++j) {
          float4 f = ap[j];
          bf16x4 o = { (bf16_t)f.x, (bf16_t)f.y, (bf16_t)f.z, (bf16_t)f.w };
          *reinterpret_cast<bf16x4*>(&Alds[swz(row, (c0 + j * 4) * 2)]) = o;
        }
      } else {
        const bf16x8* ap = reinterpret_cast<const bf16x8*>(A + (size_t)(m0 + row) * K + k0 + c0);
        #pragma unroll
        for (int j = 0; j < 2; ++j)
          *reinterpret_cast<bf16x8*>(&Alds[swz(row, (c0 + j * 8) * 2)]) = ap[j];
      }
    }
    // stage W tile transposed: Wt[n][k] (16 elems per thread, scalar transpose writes)
    {
      const int k = t >> 2, nb = (t & 3) * 16;
      const float4* wp = reinterpret_cast<const float4*>(W + (size_t)(k0 + k) * N + n0 + nb);
      #pragma unroll
      for (int j = 0; j < 4; ++j) {
        float4 f = wp[j];
        float fv[4] = { f.x, f.y, f.z, f.w };
        #pragma unroll
        for (int i = 0; i < 4; ++i) {
          const int row = nb + j * 4 + i;
          *reinterpret_cast<bf16_t*>(&Wlds[swz(row, k * 2)]) = (bf16_t)fv[i];
        }
      }
    }
    __syncthreads();
    #pragma unroll
    for (int ks = 0; ks < 2; ++ks) {
      const int kb = (ks * 32 + ((l >> 4) * 8)) * 2;
      const int arow = w * 16 + (l & 15);
      bf16x8 af = *reinterpret_cast<const bf16x8*>(&Alds[swz(arow, kb)]);
      #pragma unroll
      for (int ct = 0; ct < 4; ++ct) {
        const int brow = ct * 16 + (l & 15);
        bf16x8 bfr = *reinterpret_cast<const bf16x8*>(&Wlds[swz(brow, kb)]);
        acc[ct] = mfma16(af, bfr, acc[ct]);
      }
    }
  }
  // epilogue: C/D layout col = l&15, row = (l>>4)*4 + r
  #pragma unroll
  for (int ct = 0; ct < 4; ++ct) {
    const int col = n0 + ct * 16 + (l & 15);
    const float bv = bias[col];
    #pragma unroll
    for (int r = 0; r < 4; ++r) {
      const int row = m0 + w * 16 + ((l >> 4) * 4) + r;
      float x = acc[ct][r] + bv;
      if constexpr (RELU) x = fmaxf(x, 0.f);
      C[(size_t)row * N + col] = (OT)x;
    }
  }
}

// Flash attention: block = (b, h, 64 q rows), 4 waves x 16 rows, KV tiles of 64
__global__ __launch_bounds__(256)
void attn_kernel(const bf16_t* __restrict__ Qp, const bf16_t* __restrict__ Kp,
                 const bf16_t* __restrict__ Vp, const int* __restrict__ mask,
                 bf16_t* __restrict__ AO)
{
  __shared__ alignas(16) char Klds[64 * 128];       // [kv][d] row-major, swizzled
  __shared__ alignas(16) char Vlds[64 * 128];       // [d][kv] transposed, swizzled
  __shared__ alignas(16) char Plds[4 * 16 * 128];   // per-wave [16 q][64 kv], swizzled
  const int t = threadIdx.x, l = t & 63, w = t >> 6;
  const int bid = blockIdx.x;
  const int qt = bid & 15, h = (bid >> 4) & 7, b = bid >> 7;
  const int q0 = qt * 64;
  const size_t rb = (size_t)b * LQ;

  // Q fragments in registers (A layout: row = l&15, k = ks*32 + (l>>4)*8)
  bf16x8 qf[2];
  const int arow = q0 + w * 16 + (l & 15);
  #pragma unroll
  for (int ks = 0; ks < 2; ++ks)
    qf[ks] = *reinterpret_cast<const bf16x8*>(
        Qp + (rb + arow) * DMODEL + h * DKH + ks * 32 + (l >> 4) * 8);

  f32x4 acc[4] = {};
  float mrun[4], lsum[4];
  #pragma unroll
  for (int r = 0; r < 4; ++r) { mrun[r] = -1e30f; lsum[r] = 0.f; }

  for (int kv0 = 0; kv0 < LKk; kv0 += 64) {
    __syncthreads();
    // stage K tile [64 kv][64 d] (2 x 16B per thread)
    #pragma unroll
    for (int c = t * 2; c < t * 2 + 2; ++c) {
      const int row = c >> 3, cb = (c & 7) * 16;
      bf16x8 v = *reinterpret_cast<const bf16x8*>(
          Kp + (rb + kv0 + row) * DMODEL + h * DKH + cb / 2);
      *reinterpret_cast<bf16x8*>(&Klds[swz(row, cb)]) = v;
    }
    // stage V tile transposed: Vt[d][kv]
    #pragma unroll
    for (int c = t * 2; c < t * 2 + 2; ++c) {
      const int kv = c >> 3, d0 = (c & 7) * 8;
      bf16x8 v = *reinterpret_cast<const bf16x8*>(
          Vp + (rb + kv0 + kv) * DMODEL + h * DKH + d0);
      #pragma unroll
      for (int i = 0; i < 8; ++i)
        *reinterpret_cast<bf16_t*>(&Vlds[swz(d0 + i, kv * 2)]) = v[i];
    }
    __syncthreads();

    // S = Q K^T  (B-frag reads K rows contiguously: B[d][kv] = K[kv][d])
    f32x4 s[4] = {};
    #pragma unroll
    for (int ks = 0; ks < 2; ++ks) {
      const int kb = (ks * 32 + (l >> 4) * 8) * 2;
      #pragma unroll
      for (int ct = 0; ct < 4; ++ct) {
        bf16x8 kf = *reinterpret_cast<const bf16x8*>(&Klds[swz(ct * 16 + (l & 15), kb)]);
        s[ct] = mfma16(qf[ks], kf, s[ct]);
      }
    }

    // mask + online softmax (rows live in 16-lane groups sharing l>>4)
    #pragma unroll
    for (int r = 0; r < 4; ++r) {
      const int q = q0 + w * 16 + (l >> 4) * 4 + r;
      const int* mp = mask + ((size_t)b * LQ + q) * LKk + kv0 + (l & 15);
      float sv[4], rmax = -1e30f;
      #pragma unroll
      for (int ct = 0; ct < 4; ++ct) {
        float x = s[ct][r] * 0.125f;
        if (mp[ct * 16] == 0) x = -1e8f;
        sv[ct] = x;
        rmax = fmaxf(rmax, x);
      }
      #pragma unroll
      for (int mm = 1; mm < 16; mm <<= 1) rmax = fmaxf(rmax, __shfl_xor(rmax, mm));
      const float newm = fmaxf(mrun[r], rmax);
      const float scale = __expf(mrun[r] - newm);
      #pragma unroll
      for (int dct = 0; dct < 4; ++dct) acc[dct][r] *= scale;
      float psum = 0.f;
      #pragma unroll
      for (int ct = 0; ct < 4; ++ct) {
        const float pv = __expf(sv[ct] - newm);
        sv[ct] = pv;
        psum += pv;
      }
      #pragma unroll
      for (int mm = 1; mm < 16; mm <<= 1) psum += __shfl_xor(psum, mm);
      lsum[r] = lsum[r] * scale + psum;
      mrun[r] = newm;
      const int prow = (l >> 4) * 4 + r;
      #pragma unroll
      for (int ct = 0; ct < 4; ++ct)
        *reinterpret_cast<bf16_t*>(
            &Plds[w * 2048 + swz(prow, (ct * 16 + (l & 15)) * 2)]) = (bf16_t)sv[ct];
    }

    // O += P V   (A-frag from Plds, B-frag from transposed Vlds)
    #pragma unroll
    for (int ks = 0; ks < 2; ++ks) {
      const int kb = (ks * 32 + (l >> 4) * 8) * 2;
      bf16x8 pf = *reinterpret_cast<const bf16x8*>(&Plds[w * 2048 + swz(l & 15, kb)]);
      #pragma unroll
      for (int dct = 0; dct < 4; ++dct) {
        bf16x8 vf = *reinterpret_cast<const bf16x8*>(&Vlds[swz(dct * 16 + (l & 15), kb)]);
        acc[dct] = mfma16(pf, vf, acc[dct]);
      }
    }
  }

  #pragma unroll
  for (int dct = 0; dct < 4; ++dct) {
    const int col = h * DKH + dct * 16 + (l & 15);
    #pragma unroll
    for (int r = 0; r < 4; ++r) {
      const int q = q0 + w * 16 + (l >> 4) * 4 + r;
      AO[(rb + q) * DMODEL + col] = (bf16_t)(acc[dct][r] / lsum[r]);
    }
  }
}

extern "C" void kernel_launch(void* const* d_in, const int* in_sizes, int n_in,
                              void* d_out, int out_size, void* d_ws, size_t ws_size,
                              hipStream_t stream)
{
  const float* query = (const float*)d_in[0];
  const float* keyin = (const float*)d_in[1];
  const int*   mask  = (const int*)d_in[2];
  const float* Wq = (const float*)d_in[3];
  const float* bq = (const float*)d_in[4];
  const float* Wk = (const float*)d_in[5];
  const float* bk = (const float*)d_in[6];
  const float* Wv = (const float*)d_in[7];
  const float* bv = (const float*)d_in[8];
  const float* Wo = (const float*)d_in[9];
  const float* bo = (const float*)d_in[10];
  float* out = (float*)d_out;

  bf16_t* Qp = (bf16_t*)d_ws;
  bf16_t* Kp = Qp + (size_t)MROWS * DMODEL;
  bf16_t* Vp = Kp + (size_t)MROWS * DMODEL;
  bf16_t* AO = Vp + (size_t)MROWS * DMODEL;

  dim3 blk(256);
  dim3 gproj(DMODEL / 64, MROWS / 64);

  gemm_bias_act<256, true,  float,  bf16_t><<<gproj, blk, 0, stream>>>(query, Wq, bq, Qp, DMODEL);
  gemm_bias_act<256, true,  float,  bf16_t><<<gproj, blk, 0, stream>>>(keyin, Wk, bk, Kp, DMODEL);
  gemm_bias_act<256, true,  float,  bf16_t><<<gproj, blk, 0, stream>>>(keyin, Wv, bv, Vp, DMODEL);

  attn_kernel<<<dim3(NB * NH * (LQ / 64)), blk, 0, stream>>>(Qp, Kp, Vp, mask, AO);

  gemm_bias_act<512, false, bf16_t, float><<<gproj, blk, 0, stream>>>(AO, Wo, bo, out, DMODEL);
}